// Round 2
// baseline (654.419 us; speedup 1.0000x reference)
//
#include <hip/hip_runtime.h>

#define NNODES 50000
#define NEDGES 800000

using bf16x8  = __attribute__((ext_vector_type(8))) __bf16;
using floatx4 = __attribute__((ext_vector_type(4))) float;

__device__ __forceinline__ float bf2f(unsigned short u) {
  unsigned int v = ((unsigned int)u) << 16;
  return __builtin_bit_cast(float, v);
}
__device__ __forceinline__ unsigned short f2bf(float f) {
  unsigned int u = __builtin_bit_cast(unsigned int, f);
  u += 0x7fffu + ((u >> 16) & 1u);  // RNE
  return (unsigned short)(u >> 16);
}

__global__ void zero_int_kernel(int* __restrict__ p, int n) {
  int i = blockIdx.x * blockDim.x + threadIdx.x;
  if (i < n) p[i] = 0;
}

__global__ void degree_kernel(const int* __restrict__ dst, int* __restrict__ deg) {
  int e = blockIdx.x * blockDim.x + threadIdx.x;
  if (e < NEDGES) atomicAdd(&deg[dst[e]], 1);
}

// single block, 1024 threads: exclusive scan of deg -> row_start, cursor copy, inv_deg
__global__ void scan_kernel(const int* __restrict__ deg, int* __restrict__ row_start,
                            int* __restrict__ cursor, float* __restrict__ inv_deg) {
  __shared__ int sdata[1024];
  int tid = threadIdx.x;
  const int CH = (NNODES + 1023) / 1024;
  int b = tid * CH;
  int e = min(b + CH, NNODES);
  int s = 0;
  for (int i = b; i < e; ++i) s += deg[i];
  sdata[tid] = s;
  __syncthreads();
  for (int off = 1; off < 1024; off <<= 1) {
    int v = sdata[tid];
    int u = (tid >= off) ? sdata[tid - off] : 0;
    __syncthreads();
    sdata[tid] = v + u;
    __syncthreads();
  }
  int run = (tid == 0) ? 0 : sdata[tid - 1];
  for (int i = b; i < e; ++i) {
    int d = deg[i];
    row_start[i] = run;
    cursor[i] = run;
    inv_deg[i] = 1.0f / (float)((d > 0) ? d : 1);
    run += d;
  }
  if (tid == 1023) row_start[NNODES] = sdata[1023];
}

__global__ void fill_kernel(const int* __restrict__ src, const int* __restrict__ dst,
                            int* __restrict__ cursor, int* __restrict__ csr) {
  int e = blockIdx.x * blockDim.x + threadIdx.x;
  if (e < NEDGES) {
    int pos = atomicAdd(&cursor[dst[e]], 1);
    csr[pos] = src[e];
  }
}

// fp32 -> bf16 grid-stride convert
__global__ void conv_x_kernel(const float* __restrict__ in, unsigned short* __restrict__ out,
                              int n) {
  int i = blockIdx.x * blockDim.x + threadIdx.x;
  int stride = gridDim.x * blockDim.x;
  for (; i < n; i += stride) out[i] = f2bf(in[i]);
}

struct WPtrs {
  const float* src[6];
  unsigned short* dst[6];
  int n[6];
};

__global__ void conv_weights_kernel(WPtrs p) {
  int i = blockIdx.x * blockDim.x + threadIdx.x;
#pragma unroll
  for (int s = 0; s < 6; ++s) {
    if (i < p.n[s]) {
      p.dst[s][i] = f2bf(p.src[s][i]);
      return;
    }
    i -= p.n[s];
  }
}

// one wave per node; lane covers 2 channels (packed bf16x2 as uint)
__global__ __launch_bounds__(256) void agg_kernel(
    const unsigned short* __restrict__ hin, unsigned short* __restrict__ aggout,
    const int* __restrict__ row_start, const int* __restrict__ csr,
    const float* __restrict__ inv_deg) {
  int gw = (blockIdx.x * blockDim.x + threadIdx.x) >> 6;  // node id, exact 50000 waves
  int lane = threadIdx.x & 63;
  int s0 = row_start[gw], s1 = row_start[gw + 1];
  float a0 = 0.f, a1 = 0.f;
  int off = lane * 2;
  for (int e = s0; e < s1; ++e) {
    int sidx = csr[e];
    unsigned int v = *(const unsigned int*)(hin + (size_t)sidx * 128 + off);
    a0 += bf2f((unsigned short)(v & 0xffffu));
    a1 += bf2f((unsigned short)(v >> 16));
  }
  float idg = inv_deg[gw];
  a0 *= idg;
  a1 *= idg;
  unsigned int packed = (unsigned int)f2bf(a0) | ((unsigned int)f2bf(a1) << 16);
  *(unsigned int*)(aggout + (size_t)gw * 128 + off) = packed;
}

__device__ __forceinline__ bf16x8 load_frag(const unsigned short* p) {
  uint4 v = *(const uint4*)p;
  return __builtin_bit_cast(bf16x8, v);
}

// Fused: out[n][j] = sum_k agg[n][k]*Wl[j][k] + sum_k h[n][k]*Wr[j][k] + bl[j]
// then (optionally) ReLU + LayerNorm. One wave = 16 rows x OUTC cols, block = 4 waves.
// bl/g/beta are fp32; weights/features bf16; output bf16 (hout) or fp32 (OUTF32).
template <int NT, bool LNRELU, bool OUTF32>
__global__ __launch_bounds__(256) void fused_layer_kernel(
    const unsigned short* __restrict__ agg, const unsigned short* __restrict__ hin,
    const unsigned short* __restrict__ Wl, const float* __restrict__ bl,
    const unsigned short* __restrict__ Wr, const float* __restrict__ g,
    const float* __restrict__ beta, void* __restrict__ hout) {
  constexpr int OUTC = NT * 16;
  int wave = threadIdx.x >> 6;
  int lane = threadIdx.x & 63;
  int quad = lane >> 4;
  int m = lane & 15;
  int row0 = blockIdx.x * 64 + wave * 16;
  int arow = min(row0 + m, NNODES - 1);  // clamp: tail rows read row 49999, stores guarded
  const unsigned short* ap = agg + (size_t)arow * 128 + quad * 8;
  const unsigned short* hp = hin + (size_t)arow * 128 + quad * 8;
  bf16x8 aA[4], aH[4];
#pragma unroll
  for (int kt = 0; kt < 4; ++kt) {
    aA[kt] = load_frag(ap + kt * 32);
    aH[kt] = load_frag(hp + kt * 32);
  }
  floatx4 acc[NT];
#pragma unroll
  for (int t = 0; t < NT; ++t) {
    int n = t * 16 + m;
    const unsigned short* wlp = Wl + n * 128 + quad * 8;
    const unsigned short* wrp = Wr + n * 128 + quad * 8;
    floatx4 c = {0.f, 0.f, 0.f, 0.f};
#pragma unroll
    for (int kt = 0; kt < 4; ++kt)
      c = __builtin_amdgcn_mfma_f32_16x16x32_bf16(aA[kt], load_frag(wlp + kt * 32), c, 0, 0, 0);
#pragma unroll
    for (int kt = 0; kt < 4; ++kt)
      c = __builtin_amdgcn_mfma_f32_16x16x32_bf16(aH[kt], load_frag(wrp + kt * 32), c, 0, 0, 0);
    acc[t] = c;
  }
  float bias[NT];
#pragma unroll
  for (int t = 0; t < NT; ++t) bias[t] = bl[t * 16 + m];

  if constexpr (LNRELU) {
    // C layout: value at (row=quad*4+r, col=t*16+m). Row stats reduce over the
    // 16 lanes sharing `quad` (contiguous lane group -> shfl_xor width 16).
    float v[NT][4];
    float s1[4] = {0.f, 0.f, 0.f, 0.f};
    float s2[4] = {0.f, 0.f, 0.f, 0.f};
#pragma unroll
    for (int t = 0; t < NT; ++t)
#pragma unroll
      for (int r = 0; r < 4; ++r) {
        float x = acc[t][r] + bias[t];
        x = x > 0.f ? x : 0.f;  // ReLU before LN
        v[t][r] = x;
        s1[r] += x;
        s2[r] += x * x;
      }
#pragma unroll
    for (int r = 0; r < 4; ++r) {
#pragma unroll
      for (int msk = 1; msk < 16; msk <<= 1) {
        s1[r] += __shfl_xor(s1[r], msk, 16);
        s2[r] += __shfl_xor(s2[r], msk, 16);
      }
    }
    float gam[NT], bet[NT];
#pragma unroll
    for (int t = 0; t < NT; ++t) {
      gam[t] = g[t * 16 + m];
      bet[t] = beta[t * 16 + m];
    }
#pragma unroll
    for (int r = 0; r < 4; ++r) {
      int grow = row0 + quad * 4 + r;
      if (grow < NNODES) {
        float mu = s1[r] * (1.0f / OUTC);
        float var = s2[r] * (1.0f / OUTC) - mu * mu;
        float rs = rsqrtf(var + 1e-5f);
#pragma unroll
        for (int t = 0; t < NT; ++t) {
          float y = (v[t][r] - mu) * rs * gam[t] + bet[t];
          ((unsigned short*)hout)[(size_t)grow * OUTC + t * 16 + m] = f2bf(y);
        }
      }
    }
  } else {
#pragma unroll
    for (int r = 0; r < 4; ++r) {
      int grow = row0 + quad * 4 + r;
      if (grow < NNODES) {
#pragma unroll
        for (int t = 0; t < NT; ++t) {
          float y = acc[t][r] + bias[t];
          if constexpr (OUTF32)
            ((float*)hout)[(size_t)grow * OUTC + t * 16 + m] = y;
          else
            ((unsigned short*)hout)[(size_t)grow * OUTC + t * 16 + m] = f2bf(y);
        }
      }
    }
  }
}

extern "C" void kernel_launch(void* const* d_in, const int* in_sizes, int n_in,
                              void* d_out, int out_size, void* d_ws, size_t ws_size,
                              hipStream_t stream) {
  const float* x = (const float*)d_in[0];
  const int* ei = (const int*)d_in[1];
  const int* srcv = ei;           // edge_index[0]
  const int* dstv = ei + NEDGES;  // edge_index[1]
  const float* Wl1 = (const float*)d_in[2];
  const float* bl1 = (const float*)d_in[3];
  const float* Wr1 = (const float*)d_in[4];
  const float* Wl2 = (const float*)d_in[5];
  const float* bl2 = (const float*)d_in[6];
  const float* Wr2 = (const float*)d_in[7];
  const float* Wl3 = (const float*)d_in[8];
  const float* bl3 = (const float*)d_in[9];
  const float* Wr3 = (const float*)d_in[10];
  const float* g1 = (const float*)d_in[11];
  const float* be1 = (const float*)d_in[12];
  const float* g2 = (const float*)d_in[13];
  const float* be2 = (const float*)d_in[14];

  char* ws = (char*)d_ws;
  size_t o = 0;
  int* deg = (int*)(ws + o);         o += 200192;            // 50048 ints
  int* row_start = (int*)(ws + o);   o += 200448;            // 50001 ints (+pad)
  int* cursor = (int*)(ws + o);      o += 200192;
  float* inv_deg = (float*)(ws + o); o += 200192;
  int* csr = (int*)(ws + o);         o += 3200000;           // 800000 ints
  unsigned short* xb = (unsigned short*)(ws + o);  o += (size_t)50000 * 256;  // x in bf16
  unsigned short* wb1l = (unsigned short*)(ws + o); o += 32768;
  unsigned short* wb1r = (unsigned short*)(ws + o); o += 32768;
  unsigned short* wb2l = (unsigned short*)(ws + o); o += 32768;
  unsigned short* wb2r = (unsigned short*)(ws + o); o += 32768;
  unsigned short* wb3l = (unsigned short*)(ws + o); o += 16384;
  unsigned short* wb3r = (unsigned short*)(ws + o); o += 16384;
  unsigned short* aggb = (unsigned short*)(ws + o); o += (size_t)50000 * 256;
  unsigned short* h1 = (unsigned short*)(ws + o);   o += (size_t)50000 * 256;
  unsigned short* h2 = (unsigned short*)(ws + o);   o += (size_t)50000 * 256;

  dim3 blk(256);
  dim3 edgeGrid((NEDGES + 255) / 256);
  dim3 aggGrid(NNODES / 4);            // 4 waves/block, one node per wave
  dim3 gemmGrid((NNODES + 63) / 64);   // 64 rows per block

  // CSR build
  zero_int_kernel<<<dim3((NNODES + 255) / 256), blk, 0, stream>>>(deg, NNODES);
  degree_kernel<<<edgeGrid, blk, 0, stream>>>(dstv, deg);
  scan_kernel<<<dim3(1), dim3(1024), 0, stream>>>(deg, row_start, cursor, inv_deg);
  fill_kernel<<<edgeGrid, blk, 0, stream>>>(srcv, dstv, cursor, csr);

  // fp32 -> bf16 conversions
  conv_x_kernel<<<dim3(1024), blk, 0, stream>>>(x, xb, NNODES * 128);
  WPtrs wp;
  wp.src[0] = Wl1; wp.dst[0] = wb1l; wp.n[0] = 128 * 128;
  wp.src[1] = Wr1; wp.dst[1] = wb1r; wp.n[1] = 128 * 128;
  wp.src[2] = Wl2; wp.dst[2] = wb2l; wp.n[2] = 128 * 128;
  wp.src[3] = Wr2; wp.dst[3] = wb2r; wp.n[3] = 128 * 128;
  wp.src[4] = Wl3; wp.dst[4] = wb3l; wp.n[4] = 64 * 128;
  wp.src[5] = Wr3; wp.dst[5] = wb3r; wp.n[5] = 64 * 128;
  conv_weights_kernel<<<dim3((4 * 16384 + 2 * 8192 + 255) / 256), blk, 0, stream>>>(wp);

  // Layer 1
  agg_kernel<<<aggGrid, blk, 0, stream>>>(xb, aggb, row_start, csr, inv_deg);
  fused_layer_kernel<8, true, false><<<gemmGrid, blk, 0, stream>>>(
      aggb, xb, wb1l, bl1, wb1r, g1, be1, h1);
  // Layer 2
  agg_kernel<<<aggGrid, blk, 0, stream>>>(h1, aggb, row_start, csr, inv_deg);
  fused_layer_kernel<8, true, false><<<gemmGrid, blk, 0, stream>>>(
      aggb, h1, wb2l, bl2, wb2r, g2, be2, h2);
  // Layer 3 (no ReLU/LN), fp32 output
  agg_kernel<<<aggGrid, blk, 0, stream>>>(h2, aggb, row_start, csr, inv_deg);
  fused_layer_kernel<4, false, true><<<gemmGrid, blk, 0, stream>>>(
      aggb, h2, wb3l, bl3, wb3r, (const float*)nullptr, (const float*)nullptr, d_out);
}

// Round 3
// 404.378 us; speedup vs baseline: 1.6183x; 1.6183x over previous
//
#include <hip/hip_runtime.h>

#define NNODES 50000
#define NEDGES 800000
#define SCAN_BLOCKS 196  // ceil(50000/256)

using bf16x8  = __attribute__((ext_vector_type(8))) __bf16;
using floatx4 = __attribute__((ext_vector_type(4))) float;

__device__ __forceinline__ float bf2f(unsigned short u) {
  unsigned int v = ((unsigned int)u) << 16;
  return __builtin_bit_cast(float, v);
}
__device__ __forceinline__ unsigned short f2bf(float f) {
  unsigned int u = __builtin_bit_cast(unsigned int, f);
  u += 0x7fffu + ((u >> 16) & 1u);  // RNE
  return (unsigned short)(u >> 16);
}

__global__ void zero_int_kernel(int* __restrict__ p, int n) {
  int i = blockIdx.x * blockDim.x + threadIdx.x;
  if (i < n) p[i] = 0;
}

__global__ void degree_kernel(const int* __restrict__ dst, int* __restrict__ deg) {
  int e = blockIdx.x * blockDim.x + threadIdx.x;
  if (e < NEDGES) atomicAdd(&deg[dst[e]], 1);
}

// ---- multi-block exclusive scan of deg -> row_start/cursor/inv_deg ----
__global__ __launch_bounds__(256) void block_sum_kernel(const int* __restrict__ deg,
                                                        int* __restrict__ blocksum) {
  __shared__ int s[256];
  int i = blockIdx.x * 256 + threadIdx.x;
  s[threadIdx.x] = (i < NNODES) ? deg[i] : 0;
  __syncthreads();
  for (int off = 128; off > 0; off >>= 1) {
    if (threadIdx.x < off) s[threadIdx.x] += s[threadIdx.x + off];
    __syncthreads();
  }
  if (threadIdx.x == 0) blocksum[blockIdx.x] = s[0];
}

__global__ __launch_bounds__(256) void scan_blocksum_kernel(const int* __restrict__ blocksum,
                                                            int* __restrict__ blockoff) {
  __shared__ int s[256];
  int t = threadIdx.x;
  s[t] = (t < SCAN_BLOCKS) ? blocksum[t] : 0;
  __syncthreads();
  for (int off = 1; off < 256; off <<= 1) {
    int v = s[t];
    int u = (t >= off) ? s[t - off] : 0;
    __syncthreads();
    s[t] = v + u;
    __syncthreads();
  }
  if (t < SCAN_BLOCKS) blockoff[t] = (t == 0) ? 0 : s[t - 1];
}

__global__ __launch_bounds__(256) void apply_scan_kernel(
    const int* __restrict__ deg, const int* __restrict__ blockoff,
    int* __restrict__ row_start, int* __restrict__ cursor, float* __restrict__ inv_deg) {
  __shared__ int s[256];
  int t = threadIdx.x;
  int i = blockIdx.x * 256 + t;
  int d = (i < NNODES) ? deg[i] : 0;
  s[t] = d;
  __syncthreads();
  for (int off = 1; off < 256; off <<= 1) {
    int v = s[t];
    int u = (t >= off) ? s[t - off] : 0;
    __syncthreads();
    s[t] = v + u;
    __syncthreads();
  }
  if (i < NNODES) {
    int excl = blockoff[blockIdx.x] + s[t] - d;  // inclusive - self
    row_start[i] = excl;
    cursor[i] = excl;
    inv_deg[i] = 1.0f / (float)((d > 0) ? d : 1);
  }
  if (i == 0) row_start[NNODES] = NEDGES;
}

__global__ void fill_kernel(const int* __restrict__ src, const int* __restrict__ dst,
                            int* __restrict__ cursor, int* __restrict__ csr) {
  int e = blockIdx.x * blockDim.x + threadIdx.x;
  if (e < NEDGES) {
    int pos = atomicAdd(&cursor[dst[e]], 1);
    csr[pos] = src[e];
  }
}

// fp32 -> bf16, vectorized: float4 in, ushort4 out
__global__ void conv_x_kernel(const float4* __restrict__ in, ushort4* __restrict__ out,
                              int n4) {
  int i = blockIdx.x * blockDim.x + threadIdx.x;
  int stride = gridDim.x * blockDim.x;
  for (; i < n4; i += stride) {
    float4 v = in[i];
    ushort4 o;
    o.x = f2bf(v.x);
    o.y = f2bf(v.y);
    o.z = f2bf(v.z);
    o.w = f2bf(v.w);
    out[i] = o;
  }
}

struct WPtrs {
  const float* src[6];
  unsigned short* dst[6];
  int n[6];
};

__global__ void conv_weights_kernel(WPtrs p) {
  int i = blockIdx.x * blockDim.x + threadIdx.x;
#pragma unroll
  for (int s = 0; s < 6; ++s) {
    if (i < p.n[s]) {
      p.dst[s][i] = f2bf(p.src[s][i]);
      return;
    }
    i -= p.n[s];
  }
}

// one wave per node; lane covers 2 channels (packed bf16x2 as uint); 4x unrolled
__global__ __launch_bounds__(256) void agg_kernel(
    const unsigned short* __restrict__ hin, unsigned short* __restrict__ aggout,
    const int* __restrict__ row_start, const int* __restrict__ csr,
    const float* __restrict__ inv_deg) {
  int gw = (blockIdx.x * blockDim.x + threadIdx.x) >> 6;  // node id
  int lane = threadIdx.x & 63;
  int s0 = row_start[gw], s1 = row_start[gw + 1];
  float a0 = 0.f, a1 = 0.f;
  int off = lane * 2;
  int e = s0;
  for (; e + 4 <= s1; e += 4) {
    int i0 = csr[e], i1 = csr[e + 1], i2 = csr[e + 2], i3 = csr[e + 3];
    unsigned int v0 = *(const unsigned int*)(hin + (size_t)i0 * 128 + off);
    unsigned int v1 = *(const unsigned int*)(hin + (size_t)i1 * 128 + off);
    unsigned int v2 = *(const unsigned int*)(hin + (size_t)i2 * 128 + off);
    unsigned int v3 = *(const unsigned int*)(hin + (size_t)i3 * 128 + off);
    a0 += bf2f((unsigned short)(v0 & 0xffffu)) + bf2f((unsigned short)(v1 & 0xffffu)) +
          bf2f((unsigned short)(v2 & 0xffffu)) + bf2f((unsigned short)(v3 & 0xffffu));
    a1 += bf2f((unsigned short)(v0 >> 16)) + bf2f((unsigned short)(v1 >> 16)) +
          bf2f((unsigned short)(v2 >> 16)) + bf2f((unsigned short)(v3 >> 16));
  }
  for (; e < s1; ++e) {
    int sidx = csr[e];
    unsigned int v = *(const unsigned int*)(hin + (size_t)sidx * 128 + off);
    a0 += bf2f((unsigned short)(v & 0xffffu));
    a1 += bf2f((unsigned short)(v >> 16));
  }
  float idg = inv_deg[gw];
  a0 *= idg;
  a1 *= idg;
  unsigned int packed = (unsigned int)f2bf(a0) | ((unsigned int)f2bf(a1) << 16);
  *(unsigned int*)(aggout + (size_t)gw * 128 + off) = packed;
}

__device__ __forceinline__ bf16x8 load_frag(const unsigned short* p) {
  uint4 v = *(const uint4*)p;
  return __builtin_bit_cast(bf16x8, v);
}

// Fused: out[n][j] = sum_k agg[n][k]*Wl[j][k] + sum_k h[n][k]*Wr[j][k] + bl[j]
// then (optionally) ReLU + LayerNorm. One wave = 16 rows x OUTC cols, block = 4 waves.
template <int NT, bool LNRELU, bool OUTF32>
__global__ __launch_bounds__(256) void fused_layer_kernel(
    const unsigned short* __restrict__ agg, const unsigned short* __restrict__ hin,
    const unsigned short* __restrict__ Wl, const float* __restrict__ bl,
    const unsigned short* __restrict__ Wr, const float* __restrict__ g,
    const float* __restrict__ beta, void* __restrict__ hout) {
  constexpr int OUTC = NT * 16;
  int wave = threadIdx.x >> 6;
  int lane = threadIdx.x & 63;
  int quad = lane >> 4;
  int m = lane & 15;
  int row0 = blockIdx.x * 64 + wave * 16;
  int arow = min(row0 + m, NNODES - 1);  // clamp: tail rows read row 49999, stores guarded
  const unsigned short* ap = agg + (size_t)arow * 128 + quad * 8;
  const unsigned short* hp = hin + (size_t)arow * 128 + quad * 8;
  bf16x8 aA[4], aH[4];
#pragma unroll
  for (int kt = 0; kt < 4; ++kt) {
    aA[kt] = load_frag(ap + kt * 32);
    aH[kt] = load_frag(hp + kt * 32);
  }
  floatx4 acc[NT];
#pragma unroll
  for (int t = 0; t < NT; ++t) {
    int n = t * 16 + m;
    const unsigned short* wlp = Wl + n * 128 + quad * 8;
    const unsigned short* wrp = Wr + n * 128 + quad * 8;
    floatx4 c = {0.f, 0.f, 0.f, 0.f};
#pragma unroll
    for (int kt = 0; kt < 4; ++kt)
      c = __builtin_amdgcn_mfma_f32_16x16x32_bf16(aA[kt], load_frag(wlp + kt * 32), c, 0, 0, 0);
#pragma unroll
    for (int kt = 0; kt < 4; ++kt)
      c = __builtin_amdgcn_mfma_f32_16x16x32_bf16(aH[kt], load_frag(wrp + kt * 32), c, 0, 0, 0);
    acc[t] = c;
  }
  float bias[NT];
#pragma unroll
  for (int t = 0; t < NT; ++t) bias[t] = bl[t * 16 + m];

  if constexpr (LNRELU) {
    // C layout: value at (row=quad*4+r, col=t*16+m). Row stats reduce over the
    // 16 lanes sharing `quad` (contiguous lane group -> shfl_xor width 16).
    float v[NT][4];
    float s1[4] = {0.f, 0.f, 0.f, 0.f};
    float s2[4] = {0.f, 0.f, 0.f, 0.f};
#pragma unroll
    for (int t = 0; t < NT; ++t)
#pragma unroll
      for (int r = 0; r < 4; ++r) {
        float x = acc[t][r] + bias[t];
        x = x > 0.f ? x : 0.f;  // ReLU before LN
        v[t][r] = x;
        s1[r] += x;
        s2[r] += x * x;
      }
#pragma unroll
    for (int r = 0; r < 4; ++r) {
#pragma unroll
      for (int msk = 1; msk < 16; msk <<= 1) {
        s1[r] += __shfl_xor(s1[r], msk, 16);
        s2[r] += __shfl_xor(s2[r], msk, 16);
      }
    }
    float gam[NT], bet[NT];
#pragma unroll
    for (int t = 0; t < NT; ++t) {
      gam[t] = g[t * 16 + m];
      bet[t] = beta[t * 16 + m];
    }
#pragma unroll
    for (int r = 0; r < 4; ++r) {
      int grow = row0 + quad * 4 + r;
      if (grow < NNODES) {
        float mu = s1[r] * (1.0f / OUTC);
        float var = s2[r] * (1.0f / OUTC) - mu * mu;
        float rs = rsqrtf(var + 1e-5f);
#pragma unroll
        for (int t = 0; t < NT; ++t) {
          float y = (v[t][r] - mu) * rs * gam[t] + bet[t];
          ((unsigned short*)hout)[(size_t)grow * OUTC + t * 16 + m] = f2bf(y);
        }
      }
    }
  } else {
#pragma unroll
    for (int r = 0; r < 4; ++r) {
      int grow = row0 + quad * 4 + r;
      if (grow < NNODES) {
#pragma unroll
        for (int t = 0; t < NT; ++t) {
          float y = acc[t][r] + bias[t];
          if constexpr (OUTF32)
            ((float*)hout)[(size_t)grow * OUTC + t * 16 + m] = y;
          else
            ((unsigned short*)hout)[(size_t)grow * OUTC + t * 16 + m] = f2bf(y);
        }
      }
    }
  }
}

extern "C" void kernel_launch(void* const* d_in, const int* in_sizes, int n_in,
                              void* d_out, int out_size, void* d_ws, size_t ws_size,
                              hipStream_t stream) {
  const float* x = (const float*)d_in[0];
  const int* ei = (const int*)d_in[1];
  const int* srcv = ei;           // edge_index[0]
  const int* dstv = ei + NEDGES;  // edge_index[1]
  const float* Wl1 = (const float*)d_in[2];
  const float* bl1 = (const float*)d_in[3];
  const float* Wr1 = (const float*)d_in[4];
  const float* Wl2 = (const float*)d_in[5];
  const float* bl2 = (const float*)d_in[6];
  const float* Wr2 = (const float*)d_in[7];
  const float* Wl3 = (const float*)d_in[8];
  const float* bl3 = (const float*)d_in[9];
  const float* Wr3 = (const float*)d_in[10];
  const float* g1 = (const float*)d_in[11];
  const float* be1 = (const float*)d_in[12];
  const float* g2 = (const float*)d_in[13];
  const float* be2 = (const float*)d_in[14];

  char* ws = (char*)d_ws;
  size_t o = 0;
  int* deg = (int*)(ws + o);         o += 200192;            // 50048 ints
  int* row_start = (int*)(ws + o);   o += 200448;            // 50001 ints (+pad)
  int* cursor = (int*)(ws + o);      o += 200192;
  float* inv_deg = (float*)(ws + o); o += 200192;
  int* csr = (int*)(ws + o);         o += 3200000;           // 800000 ints
  int* blocksum = (int*)(ws + o);    o += 1024;              // 256 ints
  int* blockoff = (int*)(ws + o);    o += 1024;
  unsigned short* xb = (unsigned short*)(ws + o);  o += (size_t)50000 * 256;  // x in bf16
  unsigned short* wb1l = (unsigned short*)(ws + o); o += 32768;
  unsigned short* wb1r = (unsigned short*)(ws + o); o += 32768;
  unsigned short* wb2l = (unsigned short*)(ws + o); o += 32768;
  unsigned short* wb2r = (unsigned short*)(ws + o); o += 32768;
  unsigned short* wb3l = (unsigned short*)(ws + o); o += 16384;
  unsigned short* wb3r = (unsigned short*)(ws + o); o += 16384;
  unsigned short* aggb = (unsigned short*)(ws + o); o += (size_t)50000 * 256;
  unsigned short* h1 = (unsigned short*)(ws + o);   o += (size_t)50000 * 256;
  unsigned short* h2 = (unsigned short*)(ws + o);   o += (size_t)50000 * 256;

  dim3 blk(256);
  dim3 edgeGrid((NEDGES + 255) / 256);
  dim3 aggGrid(NNODES / 4);            // 4 waves/block, one node per wave
  dim3 gemmGrid((NNODES + 63) / 64);   // 64 rows per block
  dim3 scanGrid(SCAN_BLOCKS);

  // CSR build
  zero_int_kernel<<<dim3((NNODES + 255) / 256), blk, 0, stream>>>(deg, NNODES);
  degree_kernel<<<edgeGrid, blk, 0, stream>>>(dstv, deg);
  block_sum_kernel<<<scanGrid, blk, 0, stream>>>(deg, blocksum);
  scan_blocksum_kernel<<<dim3(1), blk, 0, stream>>>(blocksum, blockoff);
  apply_scan_kernel<<<scanGrid, blk, 0, stream>>>(deg, blockoff, row_start, cursor, inv_deg);
  fill_kernel<<<edgeGrid, blk, 0, stream>>>(srcv, dstv, cursor, csr);

  // fp32 -> bf16 conversions
  conv_x_kernel<<<dim3(1024), blk, 0, stream>>>((const float4*)x, (ushort4*)xb,
                                                NNODES * 128 / 4);
  WPtrs wp;
  wp.src[0] = Wl1; wp.dst[0] = wb1l; wp.n[0] = 128 * 128;
  wp.src[1] = Wr1; wp.dst[1] = wb1r; wp.n[1] = 128 * 128;
  wp.src[2] = Wl2; wp.dst[2] = wb2l; wp.n[2] = 128 * 128;
  wp.src[3] = Wr2; wp.dst[3] = wb2r; wp.n[3] = 128 * 128;
  wp.src[4] = Wl3; wp.dst[4] = wb3l; wp.n[4] = 64 * 128;
  wp.src[5] = Wr3; wp.dst[5] = wb3r; wp.n[5] = 64 * 128;
  conv_weights_kernel<<<dim3((4 * 16384 + 2 * 8192 + 255) / 256), blk, 0, stream>>>(wp);

  // Layer 1
  agg_kernel<<<aggGrid, blk, 0, stream>>>(xb, aggb, row_start, csr, inv_deg);
  fused_layer_kernel<8, true, false><<<gemmGrid, blk, 0, stream>>>(
      aggb, xb, wb1l, bl1, wb1r, g1, be1, h1);
  // Layer 2
  agg_kernel<<<aggGrid, blk, 0, stream>>>(h1, aggb, row_start, csr, inv_deg);
  fused_layer_kernel<8, true, false><<<gemmGrid, blk, 0, stream>>>(
      aggb, h1, wb2l, bl2, wb2r, g2, be2, h2);
  // Layer 3 (no ReLU/LN), fp32 output
  agg_kernel<<<aggGrid, blk, 0, stream>>>(h2, aggb, row_start, csr, inv_deg);
  fused_layer_kernel<4, false, true><<<gemmGrid, blk, 0, stream>>>(
      aggb, h2, wb3l, bl3, wb3r, (const float*)nullptr, (const float*)nullptr, d_out);
}

// Round 4
// 378.821 us; speedup vs baseline: 1.7275x; 1.0675x over previous
//
#include <hip/hip_runtime.h>

#define NNODES 50000
#define NEDGES 800000
#define SCAN_BLOCKS 196   // ceil(50000/256)
#define FILL_CHUNK 14336  // mult of 1024; 56 chunks cover 802816 >= NEDGES
#define FILL_NCHUNK 56

using bf16x8  = __attribute__((ext_vector_type(8))) __bf16;
using floatx4 = __attribute__((ext_vector_type(4))) float;

__device__ __forceinline__ float bf2f(unsigned short u) {
  unsigned int v = ((unsigned int)u) << 16;
  return __builtin_bit_cast(float, v);
}
__device__ __forceinline__ unsigned short f2bf(float f) {
  unsigned int u = __builtin_bit_cast(unsigned int, f);
  u += 0x7fffu + ((u >> 16) & 1u);  // RNE
  return (unsigned short)(u >> 16);
}

__global__ void zero_int_kernel(int* __restrict__ p, int n) {
  int i = blockIdx.x * blockDim.x + threadIdx.x;
  if (i < n) p[i] = 0;
}

__global__ void degree_kernel(const int* __restrict__ dst, int* __restrict__ deg) {
  int e = blockIdx.x * blockDim.x + threadIdx.x;
  if (e < NEDGES) atomicAdd(&deg[dst[e]], 1);
}

// ---- multi-block exclusive scan of deg -> row_start/cursor/inv_deg ----
__global__ __launch_bounds__(256) void block_sum_kernel(const int* __restrict__ deg,
                                                        int* __restrict__ blocksum) {
  __shared__ int s[256];
  int i = blockIdx.x * 256 + threadIdx.x;
  s[threadIdx.x] = (i < NNODES) ? deg[i] : 0;
  __syncthreads();
  for (int off = 128; off > 0; off >>= 1) {
    if (threadIdx.x < off) s[threadIdx.x] += s[threadIdx.x + off];
    __syncthreads();
  }
  if (threadIdx.x == 0) blocksum[blockIdx.x] = s[0];
}

__global__ __launch_bounds__(256) void scan_blocksum_kernel(const int* __restrict__ blocksum,
                                                            int* __restrict__ blockoff) {
  __shared__ int s[256];
  int t = threadIdx.x;
  s[t] = (t < SCAN_BLOCKS) ? blocksum[t] : 0;
  __syncthreads();
  for (int off = 1; off < 256; off <<= 1) {
    int v = s[t];
    int u = (t >= off) ? s[t - off] : 0;
    __syncthreads();
    s[t] = v + u;
    __syncthreads();
  }
  if (t < SCAN_BLOCKS) blockoff[t] = (t == 0) ? 0 : s[t - 1];
}

__global__ __launch_bounds__(256) void apply_scan_kernel(
    const int* __restrict__ deg, const int* __restrict__ blockoff,
    int* __restrict__ row_start, int* __restrict__ cursor, float* __restrict__ inv_deg) {
  __shared__ int s[256];
  int t = threadIdx.x;
  int i = blockIdx.x * 256 + t;
  int d = (i < NNODES) ? deg[i] : 0;
  s[t] = d;
  __syncthreads();
  for (int off = 1; off < 256; off <<= 1) {
    int v = s[t];
    int u = (t >= off) ? s[t - off] : 0;
    __syncthreads();
    s[t] = v + u;
    __syncthreads();
  }
  if (i < NNODES) {
    int excl = blockoff[blockIdx.x] + s[t] - d;  // inclusive - self
    row_start[i] = excl;
    cursor[i] = excl;
    inv_deg[i] = 1.0f / (float)((d > 0) ? d : 1);
  }
  if (i == 0) row_start[NNODES] = NEDGES;
}

// XCD-partitioned CSR fill: blockIdx%8 selects node partition (dst>>13, 0..6 live);
// all writers of one csr region share an XCD (round-robin heuristic), so lines
// accumulate in that XCD's L2 instead of write-through-per-store.
__global__ __launch_bounds__(256) void fill_part_kernel(const int* __restrict__ src,
                                                        const int* __restrict__ dst,
                                                        int* __restrict__ cursor,
                                                        int* __restrict__ csr) {
  int p = blockIdx.x & 7;
  if (p == 7) return;  // dst < 50000 => partition 7 empty
  int chunk = blockIdx.x >> 3;
  int e0 = chunk * FILL_CHUNK;
  int e1 = min(e0 + FILL_CHUNK, NEDGES);
  for (int base = e0 + (int)threadIdx.x * 4; base < e1; base += 256 * 4) {
    int4 d4 = *(const int4*)(dst + base);
    int4 s4 = *(const int4*)(src + base);
    if ((d4.x >> 13) == p) { int pos = atomicAdd(&cursor[d4.x], 1); csr[pos] = s4.x; }
    if ((d4.y >> 13) == p) { int pos = atomicAdd(&cursor[d4.y], 1); csr[pos] = s4.y; }
    if ((d4.z >> 13) == p) { int pos = atomicAdd(&cursor[d4.z], 1); csr[pos] = s4.z; }
    if ((d4.w >> 13) == p) { int pos = atomicAdd(&cursor[d4.w], 1); csr[pos] = s4.w; }
  }
}

// fp32 -> bf16, vectorized: float4 in, ushort4 out
__global__ void conv_x_kernel(const float4* __restrict__ in, ushort4* __restrict__ out,
                              int n4) {
  int i = blockIdx.x * blockDim.x + threadIdx.x;
  int stride = gridDim.x * blockDim.x;
  for (; i < n4; i += stride) {
    float4 v = in[i];
    ushort4 o;
    o.x = f2bf(v.x);
    o.y = f2bf(v.y);
    o.z = f2bf(v.z);
    o.w = f2bf(v.w);
    out[i] = o;
  }
}

struct WPtrs {
  const float* src[6];
  unsigned short* dst[6];
  int n[6];
};

__global__ void conv_weights_kernel(WPtrs p) {
  int i = blockIdx.x * blockDim.x + threadIdx.x;
#pragma unroll
  for (int s = 0; s < 6; ++s) {
    if (i < p.n[s]) {
      p.dst[s][i] = f2bf(p.src[s][i]);
      return;
    }
    i -= p.n[s];
  }
}

// one wave per node; half-wave per edge: lanes 0-31 edge e, lanes 32-63 edge e+1.
// Each lane loads uint2 = 4 channels; unroll 4 => 8 neighbor rows outstanding.
__global__ __launch_bounds__(256) void agg_kernel(
    const unsigned short* __restrict__ hin, unsigned short* __restrict__ aggout,
    const int* __restrict__ row_start, const int* __restrict__ csr,
    const float* __restrict__ inv_deg) {
  int gw = (blockIdx.x * blockDim.x + threadIdx.x) >> 6;  // node id
  int lane = threadIdx.x & 63;
  int half = lane >> 5;
  int c32 = lane & 31;     // channel group: channels [c32*4, c32*4+4)
  int off = c32 * 4;       // ushort offset within row
  int s0 = row_start[gw], s1 = row_start[gw + 1];
  float a0 = 0.f, a1 = 0.f, a2 = 0.f, a3 = 0.f;
  int e = s0 + half;
#define ACC(v)                                   \
  a0 += bf2f((unsigned short)((v).x & 0xffffu)); \
  a1 += bf2f((unsigned short)((v).x >> 16));     \
  a2 += bf2f((unsigned short)((v).y & 0xffffu)); \
  a3 += bf2f((unsigned short)((v).y >> 16));
  for (; e + 6 < s1; e += 8) {
    int i0 = csr[e], i1 = csr[e + 2], i2 = csr[e + 4], i3 = csr[e + 6];
    uint2 v0 = *(const uint2*)(hin + (size_t)i0 * 128 + off);
    uint2 v1 = *(const uint2*)(hin + (size_t)i1 * 128 + off);
    uint2 v2 = *(const uint2*)(hin + (size_t)i2 * 128 + off);
    uint2 v3 = *(const uint2*)(hin + (size_t)i3 * 128 + off);
    ACC(v0) ACC(v1) ACC(v2) ACC(v3)
  }
  for (; e < s1; e += 2) {
    int i0 = csr[e];
    uint2 v = *(const uint2*)(hin + (size_t)i0 * 128 + off);
    ACC(v)
  }
#undef ACC
  // combine the two half-wave partials (same channels, different edge subsets)
  a0 += __shfl_xor(a0, 32);
  a1 += __shfl_xor(a1, 32);
  a2 += __shfl_xor(a2, 32);
  a3 += __shfl_xor(a3, 32);
  if (half == 0) {
    float idg = inv_deg[gw];
    ushort4 o;
    o.x = f2bf(a0 * idg);
    o.y = f2bf(a1 * idg);
    o.z = f2bf(a2 * idg);
    o.w = f2bf(a3 * idg);
    *(ushort4*)(aggout + (size_t)gw * 128 + off) = o;
  }
}

__device__ __forceinline__ bf16x8 load_frag(const unsigned short* p) {
  uint4 v = *(const uint4*)p;
  return __builtin_bit_cast(bf16x8, v);
}

// Fused: out[n][j] = sum_k agg[n][k]*Wl[j][k] + sum_k h[n][k]*Wr[j][k] + bl[j]
// then (optionally) ReLU + LayerNorm. One wave = 16 rows x OUTC cols, block = 4 waves.
template <int NT, bool LNRELU, bool OUTF32>
__global__ __launch_bounds__(256) void fused_layer_kernel(
    const unsigned short* __restrict__ agg, const unsigned short* __restrict__ hin,
    const unsigned short* __restrict__ Wl, const float* __restrict__ bl,
    const unsigned short* __restrict__ Wr, const float* __restrict__ g,
    const float* __restrict__ beta, void* __restrict__ hout) {
  constexpr int OUTC = NT * 16;
  int wave = threadIdx.x >> 6;
  int lane = threadIdx.x & 63;
  int quad = lane >> 4;
  int m = lane & 15;
  int row0 = blockIdx.x * 64 + wave * 16;
  int arow = min(row0 + m, NNODES - 1);  // clamp: tail rows read row 49999, stores guarded
  const unsigned short* ap = agg + (size_t)arow * 128 + quad * 8;
  const unsigned short* hp = hin + (size_t)arow * 128 + quad * 8;
  bf16x8 aA[4], aH[4];
#pragma unroll
  for (int kt = 0; kt < 4; ++kt) {
    aA[kt] = load_frag(ap + kt * 32);
    aH[kt] = load_frag(hp + kt * 32);
  }
  floatx4 acc[NT];
#pragma unroll
  for (int t = 0; t < NT; ++t) {
    int n = t * 16 + m;
    const unsigned short* wlp = Wl + n * 128 + quad * 8;
    const unsigned short* wrp = Wr + n * 128 + quad * 8;
    floatx4 c = {0.f, 0.f, 0.f, 0.f};
#pragma unroll
    for (int kt = 0; kt < 4; ++kt)
      c = __builtin_amdgcn_mfma_f32_16x16x32_bf16(aA[kt], load_frag(wlp + kt * 32), c, 0, 0, 0);
#pragma unroll
    for (int kt = 0; kt < 4; ++kt)
      c = __builtin_amdgcn_mfma_f32_16x16x32_bf16(aH[kt], load_frag(wrp + kt * 32), c, 0, 0, 0);
    acc[t] = c;
  }
  float bias[NT];
#pragma unroll
  for (int t = 0; t < NT; ++t) bias[t] = bl[t * 16 + m];

  if constexpr (LNRELU) {
    // C layout: value at (row=quad*4+r, col=t*16+m). Row stats reduce over the
    // 16 lanes sharing `quad` (contiguous lane group -> shfl_xor width 16).
    float v[NT][4];
    float s1[4] = {0.f, 0.f, 0.f, 0.f};
    float s2[4] = {0.f, 0.f, 0.f, 0.f};
#pragma unroll
    for (int t = 0; t < NT; ++t)
#pragma unroll
      for (int r = 0; r < 4; ++r) {
        float x = acc[t][r] + bias[t];
        x = x > 0.f ? x : 0.f;  // ReLU before LN
        v[t][r] = x;
        s1[r] += x;
        s2[r] += x * x;
      }
#pragma unroll
    for (int r = 0; r < 4; ++r) {
#pragma unroll
      for (int msk = 1; msk < 16; msk <<= 1) {
        s1[r] += __shfl_xor(s1[r], msk, 16);
        s2[r] += __shfl_xor(s2[r], msk, 16);
      }
    }
    float gam[NT], bet[NT];
#pragma unroll
    for (int t = 0; t < NT; ++t) {
      gam[t] = g[t * 16 + m];
      bet[t] = beta[t * 16 + m];
    }
#pragma unroll
    for (int r = 0; r < 4; ++r) {
      int grow = row0 + quad * 4 + r;
      if (grow < NNODES) {
        float mu = s1[r] * (1.0f / OUTC);
        float var = s2[r] * (1.0f / OUTC) - mu * mu;
        float rs = rsqrtf(var + 1e-5f);
#pragma unroll
        for (int t = 0; t < NT; ++t) {
          float y = (v[t][r] - mu) * rs * gam[t] + bet[t];
          ((unsigned short*)hout)[(size_t)grow * OUTC + t * 16 + m] = f2bf(y);
        }
      }
    }
  } else {
#pragma unroll
    for (int r = 0; r < 4; ++r) {
      int grow = row0 + quad * 4 + r;
      if (grow < NNODES) {
#pragma unroll
        for (int t = 0; t < NT; ++t) {
          float y = acc[t][r] + bias[t];
          if constexpr (OUTF32)
            ((float*)hout)[(size_t)grow * OUTC + t * 16 + m] = y;
          else
            ((unsigned short*)hout)[(size_t)grow * OUTC + t * 16 + m] = f2bf(y);
        }
      }
    }
  }
}

extern "C" void kernel_launch(void* const* d_in, const int* in_sizes, int n_in,
                              void* d_out, int out_size, void* d_ws, size_t ws_size,
                              hipStream_t stream) {
  const float* x = (const float*)d_in[0];
  const int* ei = (const int*)d_in[1];
  const int* srcv = ei;           // edge_index[0]
  const int* dstv = ei + NEDGES;  // edge_index[1]
  const float* Wl1 = (const float*)d_in[2];
  const float* bl1 = (const float*)d_in[3];
  const float* Wr1 = (const float*)d_in[4];
  const float* Wl2 = (const float*)d_in[5];
  const float* bl2 = (const float*)d_in[6];
  const float* Wr2 = (const float*)d_in[7];
  const float* Wl3 = (const float*)d_in[8];
  const float* bl3 = (const float*)d_in[9];
  const float* Wr3 = (const float*)d_in[10];
  const float* g1 = (const float*)d_in[11];
  const float* be1 = (const float*)d_in[12];
  const float* g2 = (const float*)d_in[13];
  const float* be2 = (const float*)d_in[14];

  char* ws = (char*)d_ws;
  size_t o = 0;
  int* deg = (int*)(ws + o);         o += 200192;            // 50048 ints
  int* row_start = (int*)(ws + o);   o += 200448;            // 50001 ints (+pad)
  int* cursor = (int*)(ws + o);      o += 200192;
  float* inv_deg = (float*)(ws + o); o += 200192;
  int* csr = (int*)(ws + o);         o += 3200000;           // 800000 ints
  int* blocksum = (int*)(ws + o);    o += 1024;              // 256 ints
  int* blockoff = (int*)(ws + o);    o += 1024;
  unsigned short* xb = (unsigned short*)(ws + o);  o += (size_t)50000 * 256;  // x in bf16
  unsigned short* wb1l = (unsigned short*)(ws + o); o += 32768;
  unsigned short* wb1r = (unsigned short*)(ws + o); o += 32768;
  unsigned short* wb2l = (unsigned short*)(ws + o); o += 32768;
  unsigned short* wb2r = (unsigned short*)(ws + o); o += 32768;
  unsigned short* wb3l = (unsigned short*)(ws + o); o += 16384;
  unsigned short* wb3r = (unsigned short*)(ws + o); o += 16384;
  unsigned short* aggb = (unsigned short*)(ws + o); o += (size_t)50000 * 256;
  unsigned short* h1 = (unsigned short*)(ws + o);   o += (size_t)50000 * 256;
  unsigned short* h2 = (unsigned short*)(ws + o);   o += (size_t)50000 * 256;

  dim3 blk(256);
  dim3 edgeGrid((NEDGES + 255) / 256);
  dim3 aggGrid(NNODES / 4);            // 4 waves/block, one node per wave
  dim3 gemmGrid((NNODES + 63) / 64);   // 64 rows per block
  dim3 scanGrid(SCAN_BLOCKS);

  // CSR build
  zero_int_kernel<<<dim3((NNODES + 255) / 256), blk, 0, stream>>>(deg, NNODES);
  degree_kernel<<<edgeGrid, blk, 0, stream>>>(dstv, deg);
  block_sum_kernel<<<scanGrid, blk, 0, stream>>>(deg, blocksum);
  scan_blocksum_kernel<<<dim3(1), blk, 0, stream>>>(blocksum, blockoff);
  apply_scan_kernel<<<scanGrid, blk, 0, stream>>>(deg, blockoff, row_start, cursor, inv_deg);
  fill_part_kernel<<<dim3(FILL_NCHUNK * 8), blk, 0, stream>>>(srcv, dstv, cursor, csr);

  // fp32 -> bf16 conversions
  conv_x_kernel<<<dim3(1024), blk, 0, stream>>>((const float4*)x, (ushort4*)xb,
                                                NNODES * 128 / 4);
  WPtrs wp;
  wp.src[0] = Wl1; wp.dst[0] = wb1l; wp.n[0] = 128 * 128;
  wp.src[1] = Wr1; wp.dst[1] = wb1r; wp.n[1] = 128 * 128;
  wp.src[2] = Wl2; wp.dst[2] = wb2l; wp.n[2] = 128 * 128;
  wp.src[3] = Wr2; wp.dst[3] = wb2r; wp.n[3] = 128 * 128;
  wp.src[4] = Wl3; wp.dst[4] = wb3l; wp.n[4] = 64 * 128;
  wp.src[5] = Wr3; wp.dst[5] = wb3r; wp.n[5] = 64 * 128;
  conv_weights_kernel<<<dim3((4 * 16384 + 2 * 8192 + 255) / 256), blk, 0, stream>>>(wp);

  // Layer 1
  agg_kernel<<<aggGrid, blk, 0, stream>>>(xb, aggb, row_start, csr, inv_deg);
  fused_layer_kernel<8, true, false><<<gemmGrid, blk, 0, stream>>>(
      aggb, xb, wb1l, bl1, wb1r, g1, be1, h1);
  // Layer 2
  agg_kernel<<<aggGrid, blk, 0, stream>>>(h1, aggb, row_start, csr, inv_deg);
  fused_layer_kernel<8, true, false><<<gemmGrid, blk, 0, stream>>>(
      aggb, h1, wb2l, bl2, wb2r, g2, be2, h2);
  // Layer 3 (no ReLU/LN), fp32 output
  agg_kernel<<<aggGrid, blk, 0, stream>>>(h2, aggb, row_start, csr, inv_deg);
  fused_layer_kernel<4, false, true><<<gemmGrid, blk, 0, stream>>>(
      aggb, h2, wb3l, bl3, wb3r, (const float*)nullptr, (const float*)nullptr, d_out);
}